// Round 5
// baseline (567.029 us; speedup 1.0000x reference)
//
#include <hip/hip_runtime.h>
#include <stdint.h>

// ---------------------------------------------------------------------------
// aggregated_embedding: heap binary-tree aggregation, 11 levels.
// out = root + (elu(elu(x@WinT+b_in)@W1T+b1)@W2T+b2), x=[root,left,right]
// bf16 MFMA 16x16x32, fp32 accumulate. Round 5:
//  - 3 LDS buffers (Xs=root, Hs=left, Gs=right). Root phase FIRST; Xs stays
//    intact -> residual re-gather eliminated (root read back from Xs).
//  - children gathers issued ASYNC (global_load_lds, no dest regs) during the
//    root pass, after its last B-load (tail-kstep B preloaded upfront so the
//    last mid-pass B-load is at kstep 3; late() at kstep 4; sched_barrier
//    pins). In-order vmcnt: no post-gather B wait ever drains the gathers.
//  - biases preloaded once at kernel start (no mid-kernel scalar vmcnt).
//  - SQ_LDS_BANK_CONFLICT learned constant (4/ds_read_b128, inherent) — LDS
//    swizzle scheme from R4 kept (correct + conflict-minimal).
// ws layout:
//   [0)            Ebf   32064*256 bf16
//   [16,416,768)   Winbf 256*768  bf16   (row-major [n][k] = MFMA B-frag order)
//   [16,809,984)   W1bf  256*256  bf16
//   [16,941,056)   W2bf  256*256  bf16
//   [17,072,128)   curA  64*1024*256 bf16
//   [50,626,560)   curB  64*512*256 bf16
// ---------------------------------------------------------------------------

typedef __attribute__((ext_vector_type(8))) short short8;   // 8 x bf16 frag
typedef __attribute__((ext_vector_type(4))) float f32x4;    // MFMA C/D

typedef const __attribute__((address_space(1))) unsigned int* gas_ptr;
typedef __attribute__((address_space(3))) unsigned int* las_ptr;

#define TOK_N 4095

__device__ __forceinline__ unsigned short f32_to_bf16(float f) {
    union { float f; unsigned u; } v; v.f = f;
    return (unsigned short)((v.u + 0x7fffu + ((v.u >> 16) & 1u)) >> 16);  // RNE
}
__device__ __forceinline__ float bf16_to_f32(unsigned short u) {
    union { unsigned u; float f; } v; v.u = ((unsigned)u) << 16; return v.f;
}

__global__ void convert_f32_bf16(const float* __restrict__ E,
                                 const float* __restrict__ Win,
                                 const float* __restrict__ W1,
                                 const float* __restrict__ W2,
                                 unsigned short* __restrict__ Ebf,
                                 unsigned short* __restrict__ Winbf,
                                 unsigned short* __restrict__ W1bf,
                                 unsigned short* __restrict__ W2bf) {
    const int nE = 32064 * 256, nWin = 256 * 768, nW = 256 * 256;
    const int total4 = (nE + nWin + 2 * nW) >> 2;
    for (int i = blockIdx.x * blockDim.x + threadIdx.x; i < total4;
         i += gridDim.x * blockDim.x) {
        int idx = i << 2;
        const float* src; unsigned short* dst; int off;
        if (idx < nE)                  { src = E;   dst = Ebf;   off = idx; }
        else if (idx < nE + nWin)      { src = Win; dst = Winbf; off = idx - nE; }
        else if (idx < nE + nWin + nW) { src = W1;  dst = W1bf;  off = idx - nE - nWin; }
        else                           { src = W2;  dst = W2bf;  off = idx - nE - nWin - nW; }
        float4 f = *(const float4*)(src + off);
        ushort4 o;
        o.x = f32_to_bf16(f.x); o.y = f32_to_bf16(f.y);
        o.z = f32_to_bf16(f.z); o.w = f32_to_bf16(f.w);
        *(ushort4*)(dst + off) = o;
    }
}

// ---------------------------------------------------------------------------
// One K=256 MFMA pass. A-frags from swizzled LDS; B-frags from L2.
// B schedule: ksteps 6,7 preloaded upfront (bb_tail), ksteps 0..5 rolling
// 2-deep; last mid-pass B-load at kstep 3. late() at kstep 4 — strictly after
// every B-load of this pass, so B-waits never drain late()'s async gathers.
// ---------------------------------------------------------------------------
template<int MT, int WROW, typename F>
__device__ __forceinline__ void run_pass(const unsigned short* __restrict__ Xs,
                                         const unsigned short* __restrict__ wlane,
                                         int kbase, f32x4 (&acc)[MT][4],
                                         int l15, int q, F&& late)
{
    const int xm = l15 & 7;
    short8 bb[2][4], bt[2][4];
#pragma unroll
    for (int d = 0; d < 2; ++d)
#pragma unroll
        for (int nt = 0; nt < 4; ++nt)
            bb[d][nt] = *(const short8*)(wlane + (size_t)(nt * 16) * WROW + kbase + d * 32);
#pragma unroll
    for (int d = 0; d < 2; ++d)
#pragma unroll
        for (int nt = 0; nt < 4; ++nt)
            bt[d][nt] = *(const short8*)(wlane + (size_t)(nt * 16) * WROW + kbase + (6 + d) * 32);
#pragma unroll
    for (int k = 0; k < 8; ++k) {
        if (k == 4) {
            __builtin_amdgcn_sched_barrier(0);
            late();
            __builtin_amdgcn_sched_barrier(0);
        }
        short8 a[MT];
        const int sl = (((4 * k + q) ^ xm) << 3);       // swizzled chunk * 8
#pragma unroll
        for (int mt = 0; mt < MT; ++mt)
            a[mt] = *(const short8*)(Xs + (mt * 16 + l15) * 256 + sl);
#pragma unroll
        for (int mt = 0; mt < MT; ++mt)
#pragma unroll
            for (int nt = 0; nt < 4; ++nt)
                acc[mt][nt] = __builtin_amdgcn_mfma_f32_16x16x32_bf16(
                    a[mt], (k >= 6) ? bt[k - 6][nt] : bb[k & 1][nt],
                    acc[mt][nt], 0, 0, 0);
        if (k < 4) {                                    // reload for kstep k+2
#pragma unroll
            for (int nt = 0; nt < 4; ++nt)
                bb[k & 1][nt] = *(const short8*)(wlane + (size_t)(nt * 16) * WROW + kbase + (k + 2) * 32);
        }
    }
}

// ---------------------------------------------------------------------------
// tree_level<MT,LAST>: block = 256 thr (4 waves), R = MT*16 rows x 256 cols.
// ---------------------------------------------------------------------------
template<int MT, int LAST>
__global__ __launch_bounds__(256, 3)
void tree_level(const int* __restrict__ tokens,
                const unsigned short* __restrict__ Ebf,
                const unsigned short* __restrict__ Win,
                const unsigned short* __restrict__ W1,
                const unsigned short* __restrict__ W2,
                const float* __restrict__ b_in,
                const float* __restrict__ b1,
                const float* __restrict__ b2,
                const unsigned short* __restrict__ cur_in,
                unsigned short* __restrict__ cur_out,
                float* __restrict__ final_out,
                int L, int logL, int first)
{
    constexpr int R = MT * 16;
    __shared__ unsigned short Xs[R * 256];   // root (kept to the end)
    __shared__ unsigned short Hs[R * 256];   // left / H1 / H2
    __shared__ unsigned short Gs[R * 256];   // right / output staging

    const int tid  = threadIdx.x;
    const int lane = tid & 63;
    const int wid  = tid >> 6;
    const int l15  = lane & 15;
    const int q    = lane >> 4;
    const int n0   = wid * 64;
    const int blk  = blockIdx.x;

    // async gather of one 256-wide phase into dst (swizzled; 2 rows/instr)
    auto gather = [&](int p, unsigned short* dst) {
#pragma unroll
        for (int t = 0; t < R / 8; ++t) {
            const int base_r = wid * (R / 4) + t * 2;
            const int r = base_r + (lane >> 5);
            const unsigned short* src;
            {
                int g = blk * R + r;
                int b = g >> logL;
                int i = g - (b << logL);
                if (p == 0) {
                    int tok = tokens[b * TOK_N + (L - 1) + i];
                    src = Ebf + (size_t)tok * 256;
                } else if (first) {
                    int tok = tokens[b * TOK_N + 2047 + 2 * i + (p - 1)];
                    src = Ebf + (size_t)tok * 256;
                } else {
                    src = cur_in + ((size_t)b * (2 * L) + 2 * i + (p - 1)) * 256;
                }
            }
            const int c = (lane & 31) ^ (r & 7);         // chunk for my slot
            __builtin_amdgcn_global_load_lds(
                (gas_ptr)(const void*)(src + c * 8),
                (las_ptr)(void*)(dst + base_r * 256), 16, 0, 0);
        }
    };

    // biases preloaded once
    float bva[4], bvb[4], bvc[4];
#pragma unroll
    for (int nt = 0; nt < 4; ++nt) {
        bva[nt] = b_in[n0 + nt * 16 + l15];
        bvb[nt] = b1[n0 + nt * 16 + l15];
        bvc[nt] = b2[n0 + nt * 16 + l15];
    }

    f32x4 acc[MT][4];
    auto init_acc = [&](const float* bv) {
#pragma unroll
        for (int mt = 0; mt < MT; ++mt)
#pragma unroll
            for (int nt = 0; nt < 4; ++nt)
                acc[mt][nt] = (f32x4){bv[nt], bv[nt], bv[nt], bv[nt]};
    };
    // C-layout epilogue -> swizzled dst (elu + bf16)
    auto store_elu = [&](unsigned short* dst) {
#pragma unroll
        for (int mt = 0; mt < MT; ++mt)
#pragma unroll
            for (int nt = 0; nt < 4; ++nt)
#pragma unroll
                for (int rr = 0; rr < 4; ++rr) {
                    int row = mt * 16 + q * 4 + rr;
                    int col = n0 + nt * 16 + l15;
                    float h = acc[mt][nt][rr];
                    h = h > 0.f ? h : (__expf(h) - 1.f);
                    int slot = (col >> 3) ^ (row & 7);
                    dst[row * 256 + slot * 8 + (col & 7)] = f32_to_bf16(h);
                }
    };

    // ---- GEMM1: root pass first; children prefetched during it ----------
    gather(0, Xs);                        // root (token scatter) — serial
    __syncthreads();
    init_acc(bva);
    const unsigned short* winlane = Win + q * 8 + (size_t)(n0 + l15) * 768;
    run_pass<MT, 768>(Xs, winlane, 0, acc, l15, q, [&]() {
        gather(1, Hs);                    // left  — async, lands by next bar
        gather(2, Gs);                    // right — async, lands in ~2 passes
    });
    __syncthreads();                      // drains gathers 1+2
    run_pass<MT, 768>(Hs, winlane, 256, acc, l15, q, []() {});
    __syncthreads();
    run_pass<MT, 768>(Gs, winlane, 512, acc, l15, q, []() {});
    // no barrier needed: ep1 writes Hs, whose reads finished at previous bar
    store_elu(Hs);
    __syncthreads();

    // ---- GEMM2 ----------------------------------------------------------
    init_acc(bvb);
    run_pass<MT, 256>(Hs, W1 + q * 8 + (size_t)(n0 + l15) * 256, 0, acc, l15, q, []() {});
    __syncthreads();
    store_elu(Hs);                        // in place (barrier above)
    __syncthreads();

    // ---- GEMM3 ----------------------------------------------------------
    init_acc(bvc);
    run_pass<MT, 256>(Hs, W2 + q * 8 + (size_t)(n0 + l15) * 256, 0, acc, l15, q, []() {});

    // ---- epilogue 3: o = root(Xs) + H3 (+b2 in acc), no elu -------------
    if (LAST) {
#pragma unroll
        for (int mt = 0; mt < MT; ++mt)
#pragma unroll
            for (int nt = 0; nt < 4; ++nt)
#pragma unroll
                for (int rr = 0; rr < 4; ++rr) {
                    int row = mt * 16 + q * 4 + rr;
                    int col = n0 + nt * 16 + l15;
                    int slot = (col >> 3) ^ (row & 7);
                    float o = acc[mt][nt][rr] +
                              bf16_to_f32(Xs[row * 256 + slot * 8 + (col & 7)]);
                    final_out[(size_t)(blk * R + row) * 256 + col] = o;
                }
    } else {
        __syncthreads();                  // Gs reads (pass2) long done; Hs reads done
#pragma unroll
        for (int mt = 0; mt < MT; ++mt)
#pragma unroll
            for (int nt = 0; nt < 4; ++nt)
#pragma unroll
                for (int rr = 0; rr < 4; ++rr) {
                    int row = mt * 16 + q * 4 + rr;
                    int col = n0 + nt * 16 + l15;
                    int slot = (col >> 3) ^ (row & 7);
                    float o = acc[mt][nt][rr] +
                              bf16_to_f32(Xs[row * 256 + slot * 8 + (col & 7)]);
                    Gs[row * 256 + slot * 8 + (col & 7)] = f32_to_bf16(o);
                }
        __syncthreads();
        // coalesced bf16 store (16B chunks, de-swizzled)
        const int s   = tid & 31;
        const int sub = tid >> 5;
#pragma unroll
        for (int it = 0; it < R / 8; ++it) {
            int r = it * 8 + sub;
            int c = s ^ (r & 7);
            *(short8*)(cur_out + (size_t)(blk * R + r) * 256 + c * 8) =
                *(const short8*)(Gs + r * 256 + s * 8);
        }
    }
}

template<int MT, int LAST>
static void launch_level(const int* tokens, const unsigned short* Ebf,
                         const unsigned short* Win, const unsigned short* W1,
                         const unsigned short* W2, const float* b_in,
                         const float* b1, const float* b2,
                         const unsigned short* cin, unsigned short* cout,
                         float* out, int L, int first, hipStream_t stream) {
    int logL = 31 - __builtin_clz((unsigned)L);
    int blocks = (64 * L) / (16 * MT);
    tree_level<MT, LAST><<<dim3(blocks), dim3(256), 0, stream>>>(
        tokens, Ebf, Win, W1, W2, b_in, b1, b2, cin, cout, out, L, logL, first);
}

extern "C" void kernel_launch(void* const* d_in, const int* in_sizes, int n_in,
                              void* d_out, int out_size, void* d_ws, size_t ws_size,
                              hipStream_t stream) {
    const int*   tokens = (const int*)  d_in[0];
    const float* E      = (const float*)d_in[1];
    const float* W_in   = (const float*)d_in[2];
    const float* b_in   = (const float*)d_in[3];
    const float* W1     = (const float*)d_in[4];
    const float* b1     = (const float*)d_in[5];
    const float* W2     = (const float*)d_in[6];
    const float* b2     = (const float*)d_in[7];
    float* out = (float*)d_out;
    char* ws = (char*)d_ws;

    unsigned short* Ebf   = (unsigned short*)(ws);
    unsigned short* Winbf = (unsigned short*)(ws + 16416768);
    unsigned short* W1bf  = (unsigned short*)(ws + 16809984);
    unsigned short* W2bf  = (unsigned short*)(ws + 16941056);
    unsigned short* curA  = (unsigned short*)(ws + 17072128);
    unsigned short* curB  = (unsigned short*)(ws + 50626560);

    convert_f32_bf16<<<1024, 256, 0, stream>>>(E, W_in, W1, W2,
                                               Ebf, Winbf, W1bf, W2bf);

    const unsigned short* cin = curB;   // unused at first level
    unsigned short* cout = curA;
    int first = 1;
    for (int L = 1024; L >= 1; L >>= 1) {
        int last = (L == 1);
        if (L >= 256)
            launch_level<2, 0>(tokens, Ebf, Winbf, W1bf, W2bf, b_in, b1, b2,
                               cin, cout, nullptr, L, first, stream);
        else if (!last)
            launch_level<1, 0>(tokens, Ebf, Winbf, W1bf, W2bf, b_in, b1, b2,
                               cin, cout, nullptr, L, first, stream);
        else
            launch_level<1, 1>(tokens, Ebf, Winbf, W1bf, W2bf, b_in, b1, b2,
                               cin, cout, out, L, first, stream);
        cin = cout;
        cout = (cout == curA) ? curB : curA;
        first = 0;
    }
}